// Round 5
// baseline (523.286 us; speedup 1.0000x reference)
//
#include <hip/hip_runtime.h>

#define NN 100000
#define NE 1600000
#define MPAD 100096  // NN padded to 128-row tiles (782*128)
#define NB16 6250    // NN/16 fused agg+gemm blocks (exact)
#define HB 1563      // ceil(NE/1024) histogram blocks
#define FB 6250      // NE/256 fill blocks (exact)
#define SB 98        // ceil(NN/1024) scan blocks

typedef unsigned short ushortT;
typedef unsigned long long ull;
using sh8 = __attribute__((ext_vector_type(8))) short;   // 8 bf16 (4 VGPR) MFMA frag
using f4  = __attribute__((ext_vector_type(4))) float;   // MFMA accumulator

// ---------------- bf16 helpers ----------------

__device__ __forceinline__ unsigned short bfr(float f) {
  unsigned u = __float_as_uint(f);
  u += 0x7FFF + ((u >> 16) & 1);
  return (unsigned short)(u >> 16);
}
__device__ __forceinline__ float bf2f(unsigned short h) {
  return __uint_as_float(((unsigned)h) << 16);
}
__device__ __forceinline__ void acc8(const uint4 v, float* a) {
  a[0] += __uint_as_float(v.x << 16);
  a[1] += __uint_as_float(v.x & 0xFFFF0000u);
  a[2] += __uint_as_float(v.y << 16);
  a[3] += __uint_as_float(v.y & 0xFFFF0000u);
  a[4] += __uint_as_float(v.z << 16);
  a[5] += __uint_as_float(v.z & 0xFFFF0000u);
  a[6] += __uint_as_float(v.w << 16);
  a[7] += __uint_as_float(v.w & 0xFFFF0000u);
}
__device__ __forceinline__ sh8 hi8(const float4 a, const float4 b) {
  sh8 r;
  r[0] = (short)bfr(a.x); r[1] = (short)bfr(a.y);
  r[2] = (short)bfr(a.z); r[3] = (short)bfr(a.w);
  r[4] = (short)bfr(b.x); r[5] = (short)bfr(b.y);
  r[6] = (short)bfr(b.z); r[7] = (short)bfr(b.w);
  return r;
}

// ---------------- W pack helper ----------------
// Bp[((ks*CG + g)*64 + lane)*8 + j]; k=(ks&3)*32+(lane>>4)*8+j, n=g*16+(lane&15)
// hi for ks<4, lo residue for ks>=4.

template <int COUT>
__device__ __forceinline__ void packone(const float* __restrict__ W,
                                        ushortT* __restrict__ Bp, int i) {
  const int j = i & 7;
  const int l = (i >> 3) & 63;
  const int rest = i >> 9;
  const int g = rest % (COUT / 16);
  const int ks = rest / (COUT / 16);
  const int k = (ks & 3) * 32 + (l >> 4) * 8 + j;
  const int n = g * 16 + (l & 15);
  const float v = W[k * COUT + n];
  const unsigned short h = bfr(v);
  Bp[i] = (ks < 4) ? h : bfr(v - bf2f(h));
}

// ---------------- preprocessing v2: direct CSR build -------------------------
// Replaces bucketed scatter + per-bucket CSR (est ~100 us hidden cost: 391
// blocks, LDS scans, 6.4 MB pair round-trip). 3 fully-parallel kernels:
// hist (global atomics), scan (98x1024 Hillis), fill (1 edge/thread atomic).

__global__ __launch_bounds__(256) void k_histpack(
    const int* __restrict__ dst, int* __restrict__ deg,
    const float* __restrict__ W1, const float* __restrict__ W2,
    const float* __restrict__ W3, ushortT* __restrict__ Bp1,
    ushortT* __restrict__ Bp2, ushortT* __restrict__ Bp3) {
  if (blockIdx.x >= HB) {
    const int i = (blockIdx.x - HB) * 256 + threadIdx.x;  // 0..81919
    if (i < 32768) packone<128>(W1, Bp1, i);
    else if (i < 65536) packone<128>(W2, Bp2, i - 32768);
    else packone<64>(W3, Bp3, i - 65536);
    return;
  }
  const int base = blockIdx.x * 1024 + threadIdx.x;
#pragma unroll
  for (int k = 0; k < 4; ++k) {
    const int e = base + 256 * k;
    if (e < NE) atomicAdd(&deg[dst[e]], 1);
  }
}

// rowptr/cursor/dinv from deg. Block b: base = sum(deg[0..b*1024)) via
// strided partial + tree reduce (deg is 400 KB, L2-hot), then 1024-wide
// Hillis scan of own chunk.

__global__ __launch_bounds__(1024) void k_scan(const int* __restrict__ deg,
                                               int* __restrict__ rowptr,
                                               int* __restrict__ cursor,
                                               float* __restrict__ dinv) {
  __shared__ int sd[1024];
  const int t = threadIdx.x;
  const int b = blockIdx.x;
  const int n = b * 1024 + t;
  // bucket base = sum of all preceding degrees
  int partial = 0;
  for (int i = t; i < b * 1024; i += 1024) partial += deg[i];
  sd[t] = partial;
  __syncthreads();
  for (int off = 512; off > 0; off >>= 1) {
    if (t < off) sd[t] += sd[t + off];
    __syncthreads();
  }
  const int bbase = sd[0];
  __syncthreads();
  const int v = (n < NN) ? deg[n] : 0;
  sd[t] = v;
  __syncthreads();
  for (int off = 1; off < 1024; off <<= 1) {
    int x = (t >= off) ? sd[t - off] : 0;
    __syncthreads();
    sd[t] += x;
    __syncthreads();
  }
  const int excl = sd[t] - v;
  if (n < NN) {
    const int rp = bbase + excl;
    rowptr[n] = rp;
    cursor[n] = rp;
    dinv[n] = rsqrtf(1.0f + (float)v);  // self-loop => deg >= 1
  }
  if (b == 0 && t == 0) rowptr[NN] = NE;
}

__global__ __launch_bounds__(256) void k_fill(const int* __restrict__ src,
                                              const int* __restrict__ dst,
                                              int* __restrict__ cursor,
                                              int* __restrict__ col) {
  const int e = blockIdx.x * 256 + threadIdx.x;  // FB*256 == NE exactly
  const int d = dst[e];
  const int s = src[e];
  const int pos = atomicAdd(&cursor[d], 1);
  col[pos] = s;
}

// ---------------- MFMA GEMM (layer 1): hs1 = bf16( X @ W1 * dinv ) -----------

template <int COUT, bool FUSED>
__global__ __launch_bounds__(256) void k_gemmM(const ushortT* __restrict__ A,
                                               const float* __restrict__ X,
                                               const ushortT* __restrict__ Bp,
                                               const float* __restrict__ dinv,
                                               ushortT* __restrict__ hs) {
  constexpr int CGALL = COUT / 16;              // 8 or 4
  constexpr int RG = 2;                         // row-groups per wave (32 rows)
  constexpr int CG = 4;                         // col-groups per wave (64 cols)
  const int w = threadIdx.x >> 6;
  const int lane = threadIdx.x & 63;
  const int q = lane >> 4;
  const int c = lane & 15;
  int row0, cg0;
  if (COUT == 128) {
    row0 = blockIdx.x * 64 + (w & 1) * 32;     // block: 64 rows x 128 cols
    cg0 = (w >> 1) * 4;
  } else {
    row0 = blockIdx.x * 128 + w * 32;          // block: 128 rows x 64 cols
    cg0 = 0;
  }

  const ushortT* ap[RG];
  const float* xp[RG];
#pragma unroll
  for (int rg = 0; rg < RG; rg++) {
    const int row = row0 + rg * 16 + c;
    if (FUSED) xp[rg] = X + (size_t)min(row, NN - 1) * 128 + q * 8;
    else ap[rg] = A + (size_t)row * 128 + q * 8;
  }
  const ushortT* bp0 = Bp + (size_t)lane * 8;

  f4 acc[RG][CG];
#pragma unroll
  for (int i = 0; i < RG; i++)
#pragma unroll
    for (int j = 0; j < CG; j++) acc[i][j] = (f4){0.f, 0.f, 0.f, 0.f};

  sh8 ah[RG], bh[CG], bl[CG];
  sh8 nah[RG], nbh[CG], nbl[CG];

  auto loadA = [&](int kr, sh8 (&h)[RG]) {
#pragma unroll
    for (int rg = 0; rg < RG; rg++) {
      if (FUSED) {
        const float4 x0 = *reinterpret_cast<const float4*>(xp[rg] + kr * 32);
        const float4 x1 = *reinterpret_cast<const float4*>(xp[rg] + kr * 32 + 4);
        h[rg] = hi8(x0, x1);
      } else {
        h[rg] = *reinterpret_cast<const sh8*>(ap[rg] + kr * 32);
      }
    }
  };
  auto loadB = [&](int kr, sh8 (&h)[CG], sh8 (&l)[CG]) {
#pragma unroll
    for (int cg = 0; cg < CG; cg++) {
      h[cg] = *reinterpret_cast<const sh8*>(bp0 + (size_t)(kr * CGALL + cg0 + cg) * 512);
      l[cg] = *reinterpret_cast<const sh8*>(bp0 + (size_t)((4 + kr) * CGALL + cg0 + cg) * 512);
    }
  };

  loadA(0, ah);
  loadB(0, bh, bl);
#pragma unroll
  for (int kr = 0; kr < 4; kr++) {
    if (kr < 3) {
      loadA(kr + 1, nah);
      loadB(kr + 1, nbh, nbl);
    }
#pragma unroll
    for (int rg = 0; rg < RG; rg++)
#pragma unroll
      for (int cg = 0; cg < CG; cg++)
        acc[rg][cg] = __builtin_amdgcn_mfma_f32_16x16x32_bf16(ah[rg], bh[cg],
                                                              acc[rg][cg], 0, 0, 0);
#pragma unroll
    for (int rg = 0; rg < RG; rg++)
#pragma unroll
      for (int cg = 0; cg < CG; cg++)
        acc[rg][cg] = __builtin_amdgcn_mfma_f32_16x16x32_bf16(ah[rg], bl[cg],
                                                              acc[rg][cg], 0, 0, 0);
    if (kr < 3) {
#pragma unroll
      for (int rg = 0; rg < RG; rg++) ah[rg] = nah[rg];
#pragma unroll
      for (int cg = 0; cg < CG; cg++) { bh[cg] = nbh[cg]; bl[cg] = nbl[cg]; }
    }
  }

  // epilogue: scale by dinv[row], round to bf16, store
#pragma unroll
  for (int rg = 0; rg < RG; rg++) {
#pragma unroll
    for (int reg = 0; reg < 4; reg++) {
      const int row = row0 + rg * 16 + q * 4 + reg;
      if (row < NN) {
        const float dv = dinv[row];
#pragma unroll
        for (int cg = 0; cg < CG; cg++) {
          hs[(size_t)row * COUT + (cg0 + cg) * 16 + c] = bfr(acc[rg][cg][reg] * dv);
        }
      }
    }
  }
}

// ---------------- FUSED aggregate + next-layer GEMM (v3: 256 thr / 16 nodes) -
// Block = 16 nodes, 256 threads = 4 waves; wave w aggregates 4 nodes (short
// serial chain), rowptr/dinv prefetched via lane-parallel load + shfl.
// 256-thr granularity keeps 8 block slots/CU staggered pipeline. Results ->
// 4 KB swizzled LDS tile; GEMM: 16 rows x COUT, wave w covers UPW col-groups.

template <int COUT>
__global__ __launch_bounds__(256, 8) void k_aggemm(
    const ushortT* __restrict__ hs_in, const int* __restrict__ rowptr,
    const int* __restrict__ col, const float* __restrict__ dinv,
    const float* __restrict__ bias, const ushortT* __restrict__ Bp,
    ushortT* __restrict__ hs_out) {
  constexpr int CGALL = COUT / 16;   // 8 or 4
  constexpr int UPW = CGALL / 4;     // MFMA units per wave: 2 or 1
  __shared__ ushortT At[16 * 128];   // 4 KB bf16 tile, swizzled
  const int t = threadIdx.x;
  const int w = t >> 6;        // wave 0..3
  const int lane = t & 63;
  const int q = lane >> 4;
  const int c = lane & 15;
  const int chb = c * 8;
  const int n0 = blockIdx.x * 16;
  const int nw0 = n0 + w * 4;  // first node of this wave

  // ---- prefetch per-wave metadata (rowptr[0..4], dinv[0..3] of nw0) ----
  const int rpv = rowptr[min(nw0 + (lane & 7), NN)];      // lanes 0..4 useful
  const float dvv = dinv[min(nw0 + (lane & 3), NN - 1)];
  const float4 b0 = *reinterpret_cast<const float4*>(bias + chb);
  const float4 b1 = *reinterpret_cast<const float4*>(bias + chb + 4);

  // ---- phase 1: aggregate 4 nodes per wave into LDS ----
  for (int it = 0; it < 4; ++it) {
    const int node = nw0 + it;   // always < NN (NB16*16 == NN)
    const int r = w * 4 + it;    // LDS row 0..15
    const int beg = __shfl(rpv, it);
    const int end = __shfl(rpv, it + 1);
    const float di = __shfl(dvv, it);
    float a[8] = {};
    if (q == 0) {  // self-loop
      const uint4 v = *reinterpret_cast<const uint4*>(hs_in + (long)node * 128 + chb);
      acc8(v, a);
    }
    int j = beg;
    if (j + 8 <= end) {
      int c0 = col[j + q];
      int c1 = col[j + 4 + q];
      while (true) {
        const uint4 v0 = *reinterpret_cast<const uint4*>(hs_in + (long)c0 * 128 + chb);
        const uint4 v1 = *reinterpret_cast<const uint4*>(hs_in + (long)c1 * 128 + chb);
        j += 8;
        const bool more = (j + 8 <= end);
        int m0, m1;
        if (more) { m0 = col[j + q]; m1 = col[j + 4 + q]; }
        acc8(v0, a);
        acc8(v1, a);
        if (!more) break;
        c0 = m0; c1 = m1;
      }
    }
    if (j + 4 <= end) {
      int cc = col[j + q];
      const uint4 v = *reinterpret_cast<const uint4*>(hs_in + (long)cc * 128 + chb);
      acc8(v, a);
      j += 4;
    }
    {
      const int rem = end - j;  // 0..3
      if (q < rem) {
        int cc = col[j + q];
        const uint4 v = *reinterpret_cast<const uint4*>(hs_in + (long)cc * 128 + chb);
        acc8(v, a);
      }
    }
#pragma unroll
    for (int i = 0; i < 8; i++) a[i] += __shfl(a[i], lane ^ 32);
#pragma unroll
    for (int i = 0; i < 8; i++) a[i] += __shfl(a[i], lane ^ 16);
    if (q == 0) {
      float o[8];
      o[0] = fmaf(a[0], di, b0.x); o[1] = fmaf(a[1], di, b0.y);
      o[2] = fmaf(a[2], di, b0.z); o[3] = fmaf(a[3], di, b0.w);
      o[4] = fmaf(a[4], di, b1.x); o[5] = fmaf(a[5], di, b1.y);
      o[6] = fmaf(a[6], di, b1.z); o[7] = fmaf(a[7], di, b1.w);
#pragma unroll
      for (int i = 0; i < 8; i++) o[i] = fmaxf(o[i], 0.f);  // relu (layers 1,2)
      uint4 H;
      H.x = (unsigned)bfr(o[0]) | ((unsigned)bfr(o[1]) << 16);
      H.y = (unsigned)bfr(o[2]) | ((unsigned)bfr(o[3]) << 16);
      H.z = (unsigned)bfr(o[4]) | ((unsigned)bfr(o[5]) << 16);
      H.w = (unsigned)bfr(o[6]) | ((unsigned)bfr(o[7]) << 16);
      const unsigned bo = (unsigned)(r * 256 + c * 16) ^ (unsigned)((r & 7) << 4);
      *reinterpret_cast<uint4*>(reinterpret_cast<char*>(At) + bo) = H;
    }
  }
  __syncthreads();

  // ---- phase 2: GEMM, 16 rows x COUT; wave w owns col-groups w*UPW.. ----
  const int cg0 = w * UPW;
  const ushortT* bp0 = Bp + (size_t)lane * 8;
  const char* ab = reinterpret_cast<const char*>(At);
  const int arow = c;  // A-frag row: m = lane&15
  f4 acc[UPW];
#pragma unroll
  for (int u = 0; u < UPW; ++u) acc[u] = (f4){0.f, 0.f, 0.f, 0.f};
#pragma unroll
  for (int kr = 0; kr < 4; ++kr) {
    const unsigned bo =
        (unsigned)(arow * 256 + kr * 64 + q * 16) ^ (unsigned)((arow & 7) << 4);
    const sh8 af = *reinterpret_cast<const sh8*>(ab + bo);
#pragma unroll
    for (int u = 0; u < UPW; ++u) {
      const sh8 bh = *reinterpret_cast<const sh8*>(
          bp0 + (size_t)(kr * CGALL + cg0 + u) * 512);
      acc[u] = __builtin_amdgcn_mfma_f32_16x16x32_bf16(af, bh, acc[u], 0, 0, 0);
    }
#pragma unroll
    for (int u = 0; u < UPW; ++u) {
      const sh8 bl = *reinterpret_cast<const sh8*>(
          bp0 + (size_t)((4 + kr) * CGALL + cg0 + u) * 512);
      acc[u] = __builtin_amdgcn_mfma_f32_16x16x32_bf16(af, bl, acc[u], 0, 0, 0);
    }
  }
  // epilogue: scale by dinv[row] (pre-scale for next agg), round, store
#pragma unroll
  for (int reg = 0; reg < 4; ++reg) {
    const int row = n0 + q * 4 + reg;  // C/D row = quad*4+reg [m89]; < NN
    const float dv = dinv[row];
#pragma unroll
    for (int u = 0; u < UPW; ++u) {
      hs_out[(size_t)row * COUT + (cg0 + u) * 16 + c] = bfr(acc[u][reg] * dv);
    }
  }
}

// ---------------- final aggregation (64 ch, fp32 out) ------------------------

__global__ __launch_bounds__(256) void k_agg64(const ushortT* __restrict__ hs,
                                               const int* __restrict__ rowptr,
                                               const int* __restrict__ col,
                                               const float* __restrict__ dinv,
                                               const float* __restrict__ bias,
                                               float* __restrict__ out) {
  const int gid = blockIdx.x * 256 + threadIdx.x;
  const int node = gid >> 6;
  if (node >= NN) return;
  const int lane = threadIdx.x & 63;
  const int o8 = lane >> 3;        // eighth 0..7
  const int chb = (lane & 7) * 8;  // 8 channels per lane
  const int beg = rowptr[node];
  const int end = rowptr[node + 1];

  float a[8] = {};
  if (o8 == 0) {  // self
    const uint4 v = *reinterpret_cast<const uint4*>(hs + (long)node * 64 + chb);
    acc8(v, a);
  }

  int j = beg;
  if (j + 16 <= end) {
    int c0 = col[j + o8];
    int c1 = col[j + 8 + o8];
    while (true) {
      const uint4 v0 = *reinterpret_cast<const uint4*>(hs + (long)c0 * 64 + chb);
      const uint4 v1 = *reinterpret_cast<const uint4*>(hs + (long)c1 * 64 + chb);
      j += 16;
      const bool more = (j + 16 <= end);
      int n0, n1;
      if (more) { n0 = col[j + o8]; n1 = col[j + 8 + o8]; }
      acc8(v0, a);
      acc8(v1, a);
      if (!more) break;
      c0 = n0; c1 = n1;
    }
  }
  for (; j + 8 <= end; j += 8) {
    int c = col[j + o8];
    const uint4 v = *reinterpret_cast<const uint4*>(hs + (long)c * 64 + chb);
    acc8(v, a);
  }
  {
    const int r = end - j;  // 0..7
    if (o8 < r) {
      int c = col[j + o8];
      const uint4 v = *reinterpret_cast<const uint4*>(hs + (long)c * 64 + chb);
      acc8(v, a);
    }
  }

#pragma unroll
  for (int i = 0; i < 8; i++) a[i] += __shfl(a[i], lane ^ 32);
#pragma unroll
  for (int i = 0; i < 8; i++) a[i] += __shfl(a[i], lane ^ 16);
#pragma unroll
  for (int i = 0; i < 8; i++) a[i] += __shfl(a[i], lane ^ 8);

  if (o8 == 0) {
    const float di = dinv[node];
    const float4 b0 = *reinterpret_cast<const float4*>(bias + chb);
    const float4 b1 = *reinterpret_cast<const float4*>(bias + chb + 4);
    float4 r0, r1;
    r0.x = fmaf(a[0], di, b0.x); r0.y = fmaf(a[1], di, b0.y);
    r0.z = fmaf(a[2], di, b0.z); r0.w = fmaf(a[3], di, b0.w);
    r1.x = fmaf(a[4], di, b1.x); r1.y = fmaf(a[5], di, b1.y);
    r1.z = fmaf(a[6], di, b1.z); r1.w = fmaf(a[7], di, b1.w);
    *reinterpret_cast<float4*>(out + (long)node * 64 + chb) = r0;
    *reinterpret_cast<float4*>(out + (long)node * 64 + chb + 4) = r1;
  }
}

// ---------------- launch ----------------

extern "C" void kernel_launch(void* const* d_in, const int* in_sizes, int n_in,
                              void* d_out, int out_size, void* d_ws, size_t ws_size,
                              hipStream_t stream) {
  const float* x  = (const float*)d_in[0];
  const int* ei   = (const int*)d_in[1];
  const float* W1 = (const float*)d_in[2];
  const float* b1 = (const float*)d_in[3];
  const float* W2 = (const float*)d_in[4];
  const float* b2 = (const float*)d_in[5];
  const float* W3 = (const float*)d_in[6];
  const float* b3 = (const float*)d_in[7];
  float* out = (float*)d_out;
  const int* srcp = ei;        // edge_index[0]
  const int* dstp = ei + NE;   // edge_index[1]

  char* wsb = (char*)d_ws;
  size_t off = 0;
  auto alloc = [&](size_t bytes) -> void* {
    void* p = wsb + off;
    off += (bytes + 255) & ~(size_t)255;
    return p;
  };
  ushortT* hs1 = (ushortT*)alloc((size_t)MPAD * 128 * 2);  // bf16 layer-1 transform
  ushortT* hs2 = (ushortT*)alloc((size_t)NN * 128 * 2);    // bf16 layer-2 transform
  int*   col    = (int*)alloc((size_t)NE * 4);
  int*   rowptr = (int*)alloc((size_t)(NN + 1) * 4);
  float* dinv   = (float*)alloc((size_t)NN * 4);
  int*   deg    = (int*)alloc((size_t)NN * 4);
  int*   cursor = (int*)alloc((size_t)NN * 4);
  ushortT* Bp1 = (ushortT*)alloc((size_t)32768 * 2);  // 8 seg x 8 cg x 512
  ushortT* Bp2 = (ushortT*)alloc((size_t)32768 * 2);
  ushortT* Bp3 = (ushortT*)alloc((size_t)16384 * 2);  // 8 seg x 4 cg x 512
  // hs3 (NN*64*2 = 12.8 MB) aliases hs1: hs1 dead after k_aggemm<128> reads
  // it; k_aggemm<64> then writes hs3 there, k_agg64 reads it.
  ushortT* hs3 = hs1;
  (void)ws_size; (void)in_sizes; (void)n_in; (void)out_size;

  hipMemsetAsync(deg, 0, (size_t)NN * 4, stream);
  k_histpack<<<HB + 320, 256, 0, stream>>>(dstp, deg, W1, W2, W3, Bp1, Bp2, Bp3);
  k_scan<<<SB, 1024, 0, stream>>>(deg, rowptr, cursor, dinv);
  k_fill<<<FB, 256, 0, stream>>>(srcp, dstp, cursor, col);

  const int aggGrid = (NN * 64) / 256;   // 25000
  const int gemmGrid128 = MPAD / 64;     // 1564 (64-row blocks)

  // layer 1 transform (fused X read)
  k_gemmM<128, true><<<gemmGrid128, 256, 0, stream>>>(nullptr, x, Bp1, dinv, hs1);
  // agg layer1 + transform layer2 (fused, 256-thr / 16-node blocks)
  k_aggemm<128><<<NB16, 256, 0, stream>>>(hs1, rowptr, col, dinv, b1, Bp2, hs2);
  // agg layer2 + transform layer3 (fused, 128 -> 64)
  k_aggemm<64><<<NB16, 256, 0, stream>>>(hs2, rowptr, col, dinv, b2, Bp3, hs3);
  // final aggregation (no relu, fp32 out)
  k_agg64<<<aggGrid, 256, 0, stream>>>(hs3, rowptr, col, dinv, b3, out);
}

// Round 6
// 385.119 us; speedup vs baseline: 1.3588x; 1.3588x over previous
//
#include <hip/hip_runtime.h>

#define NN 100000
#define NE 1600000
#define NBK 391  // buckets of 256 nodes
#define BSH 8    // bucket = dst >> 8
#define MPAD 100096  // NN padded to 128-row tiles (782*128)
#define SCB 391      // ceil(NE/4096) scatter blocks
#define CAP 5120     // padded slots per bucket (expected max ~4.3K)
#define NB16 6250    // NN/16 fused agg+gemm blocks (exact)
#define G1B 1564     // gemm1 blocks (MPAD/64)

typedef unsigned short ushortT;
typedef unsigned long long ull;
using sh8 = __attribute__((ext_vector_type(8))) short;   // 8 bf16 (4 VGPR) MFMA frag
using f4  = __attribute__((ext_vector_type(4))) float;   // MFMA accumulator

// ---------------- bf16 helpers ----------------

__device__ __forceinline__ unsigned short bfr(float f) {
  unsigned u = __float_as_uint(f);
  u += 0x7FFF + ((u >> 16) & 1);
  return (unsigned short)(u >> 16);
}
__device__ __forceinline__ float bf2f(unsigned short h) {
  return __uint_as_float(((unsigned)h) << 16);
}
__device__ __forceinline__ void acc8(const uint4 v, float* a) {
  a[0] += __uint_as_float(v.x << 16);
  a[1] += __uint_as_float(v.x & 0xFFFF0000u);
  a[2] += __uint_as_float(v.y << 16);
  a[3] += __uint_as_float(v.y & 0xFFFF0000u);
  a[4] += __uint_as_float(v.z << 16);
  a[5] += __uint_as_float(v.z & 0xFFFF0000u);
  a[6] += __uint_as_float(v.w << 16);
  a[7] += __uint_as_float(v.w & 0xFFFF0000u);
}
__device__ __forceinline__ void fma8(const uint4 v, const float s, float* a) {
  a[0] = fmaf(__uint_as_float(v.x << 16), s, a[0]);
  a[1] = fmaf(__uint_as_float(v.x & 0xFFFF0000u), s, a[1]);
  a[2] = fmaf(__uint_as_float(v.y << 16), s, a[2]);
  a[3] = fmaf(__uint_as_float(v.y & 0xFFFF0000u), s, a[3]);
  a[4] = fmaf(__uint_as_float(v.z << 16), s, a[4]);
  a[5] = fmaf(__uint_as_float(v.z & 0xFFFF0000u), s, a[5]);
  a[6] = fmaf(__uint_as_float(v.w << 16), s, a[6]);
  a[7] = fmaf(__uint_as_float(v.w & 0xFFFF0000u), s, a[7]);
}
__device__ __forceinline__ sh8 hi8(const float4 a, const float4 b) {
  sh8 r;
  r[0] = (short)bfr(a.x); r[1] = (short)bfr(a.y);
  r[2] = (short)bfr(a.z); r[3] = (short)bfr(a.w);
  r[4] = (short)bfr(b.x); r[5] = (short)bfr(b.y);
  r[6] = (short)bfr(b.z); r[7] = (short)bfr(b.w);
  return r;
}

// ---------------- W pack helper ----------------
// Bp[((ks*CG + g)*64 + lane)*8 + j]; k=(ks&3)*32+(lane>>4)*8+j, n=g*16+(lane&15)
// hi for ks<4, lo residue for ks>=4.

template <int COUT>
__device__ __forceinline__ void packone(const float* __restrict__ W,
                                        ushortT* __restrict__ Bp, int i) {
  const int j = i & 7;
  const int l = (i >> 3) & 63;
  const int rest = i >> 9;
  const int g = rest % (COUT / 16);
  const int ks = rest / (COUT / 16);
  const int k = (ks & 3) * 32 + (l >> 4) * 8 + j;
  const int n = g * 16 + (l & 15);
  const float v = W[k * COUT + n];
  const unsigned short h = bfr(v);
  Bp[i] = (ks < 4) ? h : bfr(v - bf2f(h));
}

// ---------------- fused scatter (padded buckets) + weight pack ---------------
// Pairs packed to 4 B: (src << 8) | (dst & 255). R4-proven: converts random
// scatter into coalesced bucket runs (R5's direct atomics hit 64B-granule
// write amplification, 0.93 TB/s).

__global__ __launch_bounds__(256) void k_scatterpack(
    const int* __restrict__ src, const int* __restrict__ dst,
    int* __restrict__ cursor, unsigned* __restrict__ pairArr,
    const float* __restrict__ W1, const float* __restrict__ W2,
    const float* __restrict__ W3, ushortT* __restrict__ Bp1,
    ushortT* __restrict__ Bp2, ushortT* __restrict__ Bp3) {
  if (blockIdx.x >= SCB) {
    const int i = (blockIdx.x - SCB) * 256 + threadIdx.x;  // 0..81919
    if (i < 32768) packone<128>(W1, Bp1, i);
    else if (i < 65536) packone<128>(W2, Bp2, i - 32768);
    else packone<64>(W3, Bp3, i - 65536);
    return;
  }
  __shared__ int lcnt[512];   // NBK padded to 512 (zeros beyond) for paired scan
  __shared__ int lbase[512];
  __shared__ int lrank[NBK];
  __shared__ int bbase[NBK];
  __shared__ int sd2[256];
  __shared__ unsigned sorted[4096];
  __shared__ int target[4096];
  const int t = threadIdx.x;
  for (int i = t; i < 512; i += 256) lcnt[i] = 0;
  for (int i = t; i < NBK; i += 256) lrank[i] = 0;
  __syncthreads();
  const int base = blockIdx.x * 4096;
  int rs[16], rd[16];
#pragma unroll
  for (int q = 0; q < 16; q++) {
    int e = base + t + 256 * q;
    rs[q] = (e < NE) ? src[e] : -1;
    rd[q] = (e < NE) ? dst[e] : -1;
    if (rd[q] >= 0) atomicAdd(&lcnt[rd[q] >> BSH], 1);
  }
  __syncthreads();
  // 256-wide paired exclusive scan of lcnt[0..511]
  const int s0 = lcnt[2 * t];
  const int s1 = lcnt[2 * t + 1];
  sd2[t] = s0 + s1;
  __syncthreads();
  for (int off = 1; off < 256; off <<= 1) {
    int x = (t >= off) ? sd2[t - off] : 0;
    __syncthreads();
    sd2[t] += x;
    __syncthreads();
  }
  const int epair = sd2[t] - (s0 + s1);
  lbase[2 * t] = epair;
  lbase[2 * t + 1] = epair + s0;
  __syncthreads();
  for (int i = t; i < NBK; i += 256)
    if (lcnt[i] > 0) bbase[i] = atomicAdd(&cursor[i], lcnt[i]);
  __syncthreads();
#pragma unroll
  for (int q = 0; q < 16; q++) {
    if (rd[q] >= 0) {
      int b = rd[q] >> BSH;
      int r = atomicAdd(&lrank[b], 1);
      int slot = lbase[b] + r;
      sorted[slot] = ((unsigned)rs[q] << 8) | ((unsigned)rd[q] & 255u);
      target[slot] = b * CAP + bbase[b] + r;  // padded-bucket placement
    }
  }
  __syncthreads();
  const int n = min(4096, NE - base);
  for (int s = t; s < n; s += 256) pairArr[target[s]] = sorted[s];
}

// ---------------- MERGED: CSR build (blocks 0..390) || gemm1 (391+) ----------
// gemm1 (X@W1, UNSCALED — dinv applied per-edge in aggemm<128>) has no
// dependency on the CSR, so it fills the CUs while the 391 low-parallelism
// buildcsr blocks run their scans. Saves gemm1's ~25 us of serial time.

__global__ __launch_bounds__(256) void k_csrgemm1(
    const unsigned* __restrict__ pairArr, const int* __restrict__ cnt,
    float* __restrict__ dinv, int* __restrict__ rowptr, int* __restrict__ col,
    const float* __restrict__ X, const ushortT* __restrict__ Bp,
    ushortT* __restrict__ hs) {
  __shared__ int lc[256];
  __shared__ int sd[256];
  __shared__ int bc[NBK];
  const int t = threadIdx.x;
  if (blockIdx.x < NBK) {
    // ---- buildcsr arm (R4 verbatim) ----
    const int b = blockIdx.x;
    const int n0 = b << BSH;
    for (int i = t; i < NBK; i += 256) bc[i] = cnt[i];
    lc[t] = 0;
    __syncthreads();
    int partial = 0;
    for (int i = t; i < b; i += 256) partial += bc[i];
    sd[t] = partial;
    __syncthreads();
    for (int off = 128; off > 0; off >>= 1) {
      if (t < off) sd[t] += sd[t + off];
      __syncthreads();
    }
    const int ebeg = sd[0];
    const int myCnt = bc[b];
    __syncthreads();
    const unsigned* pb = pairArr + (size_t)b * CAP;
    for (int i = t; i < myCnt; i += 256)
      atomicAdd(&lc[pb[i] & 255u], 1);
    __syncthreads();
    const int v = lc[t];
    sd[t] = v;
    __syncthreads();
    for (int off = 1; off < 256; off <<= 1) {
      int x = (t >= off) ? sd[t - off] : 0;
      __syncthreads();
      sd[t] += x;
      __syncthreads();
    }
    const int excl = sd[t] - v;
    lc[t] = excl;
    const int node = n0 + t;
    if (node < NN) {
      rowptr[node] = ebeg + excl;
      dinv[node] = rsqrtf(1.0f + (float)v);  // self-loop => deg >= 1
    }
    if (b == 0 && t == 0) rowptr[NN] = NE;
    __syncthreads();
    for (int i = t; i < myCnt; i += 256) {
      unsigned p = pb[i];
      int d = (int)(p & 255u);
      int srcv = (int)(p >> 8);
      int pos = atomicAdd(&lc[d], 1);
      col[ebeg + pos] = srcv;
    }
    return;
  }
  // ---- gemm1 arm: hs1 = bf16( X @ W1 ), unscaled ----
  constexpr int CGALL = 8;  // 128/16
  constexpr int RG = 2;
  constexpr int CG = 4;
  const int bid = blockIdx.x - NBK;
  const int w = t >> 6;
  const int lane = t & 63;
  const int q = lane >> 4;
  const int c = lane & 15;
  const int row0 = bid * 64 + (w & 1) * 32;
  const int cg0 = (w >> 1) * 4;

  const float* xp[RG];
#pragma unroll
  for (int rg = 0; rg < RG; rg++) {
    const int row = row0 + rg * 16 + c;
    xp[rg] = X + (size_t)min(row, NN - 1) * 128 + q * 8;
  }
  const ushortT* bp0 = Bp + (size_t)lane * 8;

  f4 acc[RG][CG];
#pragma unroll
  for (int i = 0; i < RG; i++)
#pragma unroll
    for (int j = 0; j < CG; j++) acc[i][j] = (f4){0.f, 0.f, 0.f, 0.f};

  sh8 ah[RG], bh[CG], bl[CG];
  sh8 nah[RG], nbh[CG], nbl[CG];

  auto loadA = [&](int kr, sh8 (&h)[RG]) {
#pragma unroll
    for (int rg = 0; rg < RG; rg++) {
      const float4 x0 = *reinterpret_cast<const float4*>(xp[rg] + kr * 32);
      const float4 x1 = *reinterpret_cast<const float4*>(xp[rg] + kr * 32 + 4);
      h[rg] = hi8(x0, x1);
    }
  };
  auto loadB = [&](int kr, sh8 (&h)[CG], sh8 (&l)[CG]) {
#pragma unroll
    for (int cg = 0; cg < CG; cg++) {
      h[cg] = *reinterpret_cast<const sh8*>(bp0 + (size_t)(kr * CGALL + cg0 + cg) * 512);
      l[cg] = *reinterpret_cast<const sh8*>(bp0 + (size_t)((4 + kr) * CGALL + cg0 + cg) * 512);
    }
  };

  loadA(0, ah);
  loadB(0, bh, bl);
#pragma unroll
  for (int kr = 0; kr < 4; kr++) {
    if (kr < 3) {
      loadA(kr + 1, nah);
      loadB(kr + 1, nbh, nbl);
    }
#pragma unroll
    for (int rg = 0; rg < RG; rg++)
#pragma unroll
      for (int cg = 0; cg < CG; cg++)
        acc[rg][cg] = __builtin_amdgcn_mfma_f32_16x16x32_bf16(ah[rg], bh[cg],
                                                              acc[rg][cg], 0, 0, 0);
#pragma unroll
    for (int rg = 0; rg < RG; rg++)
#pragma unroll
      for (int cg = 0; cg < CG; cg++)
        acc[rg][cg] = __builtin_amdgcn_mfma_f32_16x16x32_bf16(ah[rg], bl[cg],
                                                              acc[rg][cg], 0, 0, 0);
    if (kr < 3) {
#pragma unroll
      for (int rg = 0; rg < RG; rg++) ah[rg] = nah[rg];
#pragma unroll
      for (int cg = 0; cg < CG; cg++) { bh[cg] = nbh[cg]; bl[cg] = nbl[cg]; }
    }
  }

#pragma unroll
  for (int rg = 0; rg < RG; rg++) {
#pragma unroll
    for (int reg = 0; reg < 4; reg++) {
      const int row = row0 + rg * 16 + q * 4 + reg;
      if (row < NN) {
#pragma unroll
        for (int cg = 0; cg < CG; cg++) {
          hs[(size_t)row * 128 + (cg0 + cg) * 16 + c] = bfr(acc[rg][cg][reg]);
        }
      }
    }
  }
}

// ---------------- FUSED aggregate + next-layer GEMM (v4: barrier-free) -------
// Each wave owns 4 nodes end-to-end: gather (4 quads = 4 edges in flight) into
// a PRIVATE 1 KB LDS strip (4 rows x 128ch, XOR-swizzled), wave-local
// lgkmcnt(0) fence (no __syncthreads — R4's block barrier idled resident
// waves on the slowest of 4 waves: same 72% occupancy as agg128 but 2.87 vs
// 3.46 TB/s). GEMM: wave MFMAs its 4 rows with A rows replicated rr=c&3
// (MFMA rows independent; rows 4-15 discarded — MfmaUtil was 3%, 4x matrix
// waste is free). acc kept to 16 VGPR via cg-half passes.
// ESCALE: hs_in is UNSCALED; apply dinv[src] per edge (dinv is L2-resident).

template <int COUT, bool ESCALE>
__global__ __launch_bounds__(256, 6) void k_aggemm(
    const ushortT* __restrict__ hs_in, const int* __restrict__ rowptr,
    const int* __restrict__ col, const float* __restrict__ dinv,
    const float* __restrict__ bias, const ushortT* __restrict__ Bp,
    ushortT* __restrict__ hs_out) {
  constexpr int CGALL = COUT / 16;   // 8 or 4
  __shared__ ushortT At[4 * 512];    // 4 waves x (4 rows x 128 ch) bf16, 4 KB
  const int t = threadIdx.x;
  const int w = t >> 6;        // wave 0..3
  const int lane = t & 63;
  const int q = lane >> 4;
  const int c = lane & 15;
  const int chb = c * 8;
  const int nw0 = blockIdx.x * 16 + w * 4;  // wave's first node; nw0+3 < NN

  // per-wave metadata prefetch: rowptr[nw0..nw0+4], dinv[nw0..nw0+3]
  const int rpv = rowptr[min(nw0 + (lane & 7), NN)];
  const float dvv = dinv[min(nw0 + (lane & 3), NN - 1)];
  const float4 b0 = *reinterpret_cast<const float4*>(bias + chb);
  const float4 b1 = *reinterpret_cast<const float4*>(bias + chb + 4);
  char* const myAt = reinterpret_cast<char*>(At) + w * 1024;

  // ---- phase 1: gather 4 nodes into private LDS strip ----
  for (int it = 0; it < 4; ++it) {
    const int node = nw0 + it;
    const int beg = __shfl(rpv, it);
    const int end = __shfl(rpv, it + 1);
    const float di = __shfl(dvv, it);
    float a[8] = {};
    if (q == 0) {  // self-loop
      const uint4 v = *reinterpret_cast<const uint4*>(hs_in + (long)node * 128 + chb);
      if (ESCALE) fma8(v, di, a); else acc8(v, a);
    }
    int j = beg;
    if (j + 8 <= end) {
      int c0 = col[j + q];
      int c1 = col[j + 4 + q];
      float d0 = 0.f, d1 = 0.f;
      if (ESCALE) { d0 = dinv[c0]; d1 = dinv[c1]; }
      while (true) {
        const uint4 v0 = *reinterpret_cast<const uint4*>(hs_in + (long)c0 * 128 + chb);
        const uint4 v1 = *reinterpret_cast<const uint4*>(hs_in + (long)c1 * 128 + chb);
        j += 8;
        const bool more = (j + 8 <= end);
        int m0, m1;
        float e0 = 0.f, e1 = 0.f;
        if (more) {
          m0 = col[j + q]; m1 = col[j + 4 + q];
          if (ESCALE) { e0 = dinv[m0]; e1 = dinv[m1]; }
        }
        if (ESCALE) { fma8(v0, d0, a); fma8(v1, d1, a); }
        else { acc8(v0, a); acc8(v1, a); }
        if (!more) break;
        c0 = m0; c1 = m1; d0 = e0; d1 = e1;
      }
    }
    if (j + 4 <= end) {
      int cc = col[j + q];
      float ds = ESCALE ? dinv[cc] : 0.f;
      const uint4 v = *reinterpret_cast<const uint4*>(hs_in + (long)cc * 128 + chb);
      if (ESCALE) fma8(v, ds, a); else acc8(v, a);
      j += 4;
    }
    {
      const int rem = end - j;  // 0..3
      if (q < rem) {
        int cc = col[j + q];
        float ds = ESCALE ? dinv[cc] : 0.f;
        const uint4 v = *reinterpret_cast<const uint4*>(hs_in + (long)cc * 128 + chb);
        if (ESCALE) fma8(v, ds, a); else acc8(v, a);
      }
    }
#pragma unroll
    for (int i = 0; i < 8; i++) a[i] += __shfl(a[i], lane ^ 32);
#pragma unroll
    for (int i = 0; i < 8; i++) a[i] += __shfl(a[i], lane ^ 16);
    if (q == 0) {
      float o[8];
      o[0] = fmaf(a[0], di, b0.x); o[1] = fmaf(a[1], di, b0.y);
      o[2] = fmaf(a[2], di, b0.z); o[3] = fmaf(a[3], di, b0.w);
      o[4] = fmaf(a[4], di, b1.x); o[5] = fmaf(a[5], di, b1.y);
      o[6] = fmaf(a[6], di, b1.z); o[7] = fmaf(a[7], di, b1.w);
#pragma unroll
      for (int i = 0; i < 8; i++) o[i] = fmaxf(o[i], 0.f);  // relu (layers 1,2)
      uint4 H;
      H.x = (unsigned)bfr(o[0]) | ((unsigned)bfr(o[1]) << 16);
      H.y = (unsigned)bfr(o[2]) | ((unsigned)bfr(o[3]) << 16);
      H.z = (unsigned)bfr(o[4]) | ((unsigned)bfr(o[5]) << 16);
      H.w = (unsigned)bfr(o[6]) | ((unsigned)bfr(o[7]) << 16);
      *reinterpret_cast<uint4*>(myAt + ((unsigned)(it * 256 + c * 16) ^ (unsigned)(it << 4))) = H;
    }
  }
  // wave-local fence: own LDS writes visible to own lanes (no block barrier)
  asm volatile("s_waitcnt lgkmcnt(0)" ::: "memory");
  __builtin_amdgcn_sched_barrier(0);

  // ---- phase 2: per-wave GEMM, 4 valid rows x COUT ----
  const ushortT* bp0 = Bp + (size_t)lane * 8;
  const int rr = c & 3;  // A row replicated for m>=4 (outputs discarded)
  sh8 af[4];
#pragma unroll
  for (int kr = 0; kr < 4; ++kr) {
    const unsigned bo = (unsigned)((rr * 256 + kr * 64 + q * 16) ^ (rr << 4));
    af[kr] = *reinterpret_cast<const sh8*>(myAt + bo);
  }
  const float dvr0 = __shfl(dvv, 0), dvr1 = __shfl(dvv, 1),
              dvr2 = __shfl(dvv, 2), dvr3 = __shfl(dvv, 3);
#pragma unroll 1
  for (int ph = 0; ph < CGALL / 4; ++ph) {
    f4 acc[4];
#pragma unroll
    for (int u = 0; u < 4; ++u) acc[u] = (f4){0.f, 0.f, 0.f, 0.f};
#pragma unroll
    for (int kr = 0; kr < 4; ++kr) {
#pragma unroll
      for (int u = 0; u < 4; ++u) {
        const sh8 bh = *reinterpret_cast<const sh8*>(
            bp0 + (size_t)(kr * CGALL + ph * 4 + u) * 512);
        acc[u] = __builtin_amdgcn_mfma_f32_16x16x32_bf16(af[kr], bh, acc[u], 0, 0, 0);
      }
#pragma unroll
      for (int u = 0; u < 4; ++u) {
        const sh8 bl = *reinterpret_cast<const sh8*>(
            bp0 + (size_t)((4 + kr) * CGALL + ph * 4 + u) * 512);
        acc[u] = __builtin_amdgcn_mfma_f32_16x16x32_bf16(af[kr], bl, acc[u], 0, 0, 0);
      }
    }
    // D rows 0..3 live in q==0 lanes (row = q*4+reg); scale by dinv, store
    if (q == 0) {
#pragma unroll
      for (int u = 0; u < 4; ++u) {
        const int cc0 = (ph * 4 + u) * 16 + c;
        hs_out[(size_t)(nw0 + 0) * COUT + cc0] = bfr(acc[u][0] * dvr0);
        hs_out[(size_t)(nw0 + 1) * COUT + cc0] = bfr(acc[u][1] * dvr1);
        hs_out[(size_t)(nw0 + 2) * COUT + cc0] = bfr(acc[u][2] * dvr2);
        hs_out[(size_t)(nw0 + 3) * COUT + cc0] = bfr(acc[u][3] * dvr3);
      }
    }
  }
}

// ---------------- final aggregation (64 ch, fp32 out) ------------------------

__global__ __launch_bounds__(256) void k_agg64(const ushortT* __restrict__ hs,
                                               const int* __restrict__ rowptr,
                                               const int* __restrict__ col,
                                               const float* __restrict__ dinv,
                                               const float* __restrict__ bias,
                                               float* __restrict__ out) {
  const int gid = blockIdx.x * 256 + threadIdx.x;
  const int node = gid >> 6;
  if (node >= NN) return;
  const int lane = threadIdx.x & 63;
  const int o8 = lane >> 3;        // eighth 0..7
  const int chb = (lane & 7) * 8;  // 8 channels per lane
  const int beg = rowptr[node];
  const int end = rowptr[node + 1];

  float a[8] = {};
  if (o8 == 0) {  // self
    const uint4 v = *reinterpret_cast<const uint4*>(hs + (long)node * 64 + chb);
    acc8(v, a);
  }

  int j = beg;
  if (j + 16 <= end) {
    int c0 = col[j + o8];
    int c1 = col[j + 8 + o8];
    while (true) {
      const uint4 v0 = *reinterpret_cast<const uint4*>(hs + (long)c0 * 64 + chb);
      const uint4 v1 = *reinterpret_cast<const uint4*>(hs + (long)c1 * 64 + chb);
      j += 16;
      const bool more = (j + 16 <= end);
      int n0, n1;
      if (more) { n0 = col[j + o8]; n1 = col[j + 8 + o8]; }
      acc8(v0, a);
      acc8(v1, a);
      if (!more) break;
      c0 = n0; c1 = n1;
    }
  }
  for (; j + 8 <= end; j += 8) {
    int c = col[j + o8];
    const uint4 v = *reinterpret_cast<const uint4*>(hs + (long)c * 64 + chb);
    acc8(v, a);
  }
  {
    const int r = end - j;  // 0..7
    if (o8 < r) {
      int c = col[j + o8];
      const uint4 v = *reinterpret_cast<const uint4*>(hs + (long)c * 64 + chb);
      acc8(v, a);
    }
  }

#pragma unroll
  for (int i = 0; i < 8; i++) a[i] += __shfl(a[i], lane ^ 32);
#pragma unroll
  for (int i = 0; i < 8; i++) a[i] += __shfl(a[i], lane ^ 16);
#pragma unroll
  for (int i = 0; i < 8; i++) a[i] += __shfl(a[i], lane ^ 8);

  if (o8 == 0) {
    const float di = dinv[node];
    const float4 b0 = *reinterpret_cast<const float4*>(bias + chb);
    const float4 b1 = *reinterpret_cast<const float4*>(bias + chb + 4);
    float4 r0, r1;
    r0.x = fmaf(a[0], di, b0.x); r0.y = fmaf(a[1], di, b0.y);
    r0.z = fmaf(a[2], di, b0.z); r0.w = fmaf(a[3], di, b0.w);
    r1.x = fmaf(a[4], di, b1.x); r1.y = fmaf(a[5], di, b1.y);
    r1.z = fmaf(a[6], di, b1.z); r1.w = fmaf(a[7], di, b1.w);
    *reinterpret_cast<float4*>(out + (long)node * 64 + chb) = r0;
    *reinterpret_cast<float4*>(out + (long)node * 64 + chb + 4) = r1;
  }
}

// ---------------- launch ----------------

extern "C" void kernel_launch(void* const* d_in, const int* in_sizes, int n_in,
                              void* d_out, int out_size, void* d_ws, size_t ws_size,
                              hipStream_t stream) {
  const float* x  = (const float*)d_in[0];
  const int* ei   = (const int*)d_in[1];
  const float* W1 = (const float*)d_in[2];
  const float* b1 = (const float*)d_in[3];
  const float* W2 = (const float*)d_in[4];
  const float* b2 = (const float*)d_in[5];
  const float* W3 = (const float*)d_in[6];
  const float* b3 = (const float*)d_in[7];
  float* out = (float*)d_out;
  const int* srcp = ei;        // edge_index[0]
  const int* dstp = ei + NE;   // edge_index[1]

  char* wsb = (char*)d_ws;
  size_t off = 0;
  auto alloc = [&](size_t bytes) -> void* {
    void* p = wsb + off;
    off += (bytes + 255) & ~(size_t)255;
    return p;
  };
  ushortT* hs1 = (ushortT*)alloc((size_t)MPAD * 128 * 2);  // bf16 layer-1 transform
  ushortT* hs2 = (ushortT*)alloc((size_t)NN * 128 * 2);    // bf16 layer-2 transform
  int*   col    = (int*)alloc((size_t)NE * 4);
  int*   rowptr = (int*)alloc((size_t)(NN + 1) * 4);
  float* dinv   = (float*)alloc((size_t)NN * 4);
  int*   cursor = (int*)alloc((size_t)NBK * 4);
  ushortT* Bp1 = (ushortT*)alloc((size_t)32768 * 2);  // 8 seg x 8 cg x 512
  ushortT* Bp2 = (ushortT*)alloc((size_t)32768 * 2);
  ushortT* Bp3 = (ushortT*)alloc((size_t)16384 * 2);  // 8 seg x 4 cg x 512
  // Aliases (sequential-kernel lifetimes):
  //   pairArr (391*5120*4 = 8 MB) lives in hs2: written by scatterpack, read
  //     by csrgemm1's buildcsr arm, clobbered by k_aggemm<128>'s hs2 write.
  //   hs3 (NN*64*2 = 12.8 MB) lives in hs1: hs1 dead after k_aggemm<128>
  //     reads it; k_aggemm<64> then writes hs3 there, k_agg64 reads it.
  unsigned* pairArr = (unsigned*)hs2;
  ushortT* hs3 = hs1;
  (void)ws_size; (void)in_sizes; (void)n_in; (void)out_size;

  hipMemsetAsync(cursor, 0, (size_t)NBK * 4, stream);
  k_scatterpack<<<SCB + 320, 256, 0, stream>>>(srcp, dstp, cursor, pairArr,
                                               W1, W2, W3, Bp1, Bp2, Bp3);
  // CSR build (391 blocks) overlapped with layer-1 transform (1564 blocks)
  k_csrgemm1<<<NBK + G1B, 256, 0, stream>>>(pairArr, cursor, dinv, rowptr, col,
                                            x, Bp1, hs1);

  const int aggGrid = (NN * 64) / 256;   // 25000

  // agg layer1 (edge-scaled: hs1 unscaled) + transform layer2
  k_aggemm<128, true><<<NB16, 256, 0, stream>>>(hs1, rowptr, col, dinv, b1, Bp2, hs2);
  // agg layer2 (hs2 pre-scaled) + transform layer3 (128 -> 64)
  k_aggemm<64, false><<<NB16, 256, 0, stream>>>(hs2, rowptr, col, dinv, b2, Bp3, hs3);
  // final aggregation (no relu, fp32 out)
  k_agg64<<<aggGrid, 256, 0, stream>>>(hs3, rowptr, col, dinv, b3, out);
}

// Round 8
// 348.992 us; speedup vs baseline: 1.4994x; 1.1035x over previous
//
#include <hip/hip_runtime.h>

#define NN 100000
#define NE 1600000
#define NBK 391  // buckets of 256 nodes
#define BSH 8    // bucket = dst >> 8
#define MPAD 100096  // NN padded to 128-row tiles (782*128)
#define SCB 391      // ceil(NE/4096) scatter blocks
#define CAP 5120     // padded slots per bucket (expected max ~4.3K)
#define NB16 6250    // NN/16 fused agg+gemm blocks (exact)
#define G1B 1564     // gemm1 blocks (MPAD/64)

typedef unsigned short ushortT;
typedef unsigned long long ull;
using sh8 = __attribute__((ext_vector_type(8))) short;   // 8 bf16 (4 VGPR) MFMA frag
using f4  = __attribute__((ext_vector_type(4))) float;   // MFMA accumulator

// ---------------- bf16 helpers ----------------

__device__ __forceinline__ unsigned short bfr(float f) {
  unsigned u = __float_as_uint(f);
  u += 0x7FFF + ((u >> 16) & 1);
  return (unsigned short)(u >> 16);
}
__device__ __forceinline__ float bf2f(unsigned short h) {
  return __uint_as_float(((unsigned)h) << 16);
}
__device__ __forceinline__ void acc8(const uint4 v, float* a) {
  a[0] += __uint_as_float(v.x << 16);
  a[1] += __uint_as_float(v.x & 0xFFFF0000u);
  a[2] += __uint_as_float(v.y << 16);
  a[3] += __uint_as_float(v.y & 0xFFFF0000u);
  a[4] += __uint_as_float(v.z << 16);
  a[5] += __uint_as_float(v.z & 0xFFFF0000u);
  a[6] += __uint_as_float(v.w << 16);
  a[7] += __uint_as_float(v.w & 0xFFFF0000u);
}
__device__ __forceinline__ void fma8(const uint4 v, const float s, float* a) {
  a[0] = fmaf(__uint_as_float(v.x << 16), s, a[0]);
  a[1] = fmaf(__uint_as_float(v.x & 0xFFFF0000u), s, a[1]);
  a[2] = fmaf(__uint_as_float(v.y << 16), s, a[2]);
  a[3] = fmaf(__uint_as_float(v.y & 0xFFFF0000u), s, a[3]);
  a[4] = fmaf(__uint_as_float(v.z << 16), s, a[4]);
  a[5] = fmaf(__uint_as_float(v.z & 0xFFFF0000u), s, a[5]);
  a[6] = fmaf(__uint_as_float(v.w << 16), s, a[6]);
  a[7] = fmaf(__uint_as_float(v.w & 0xFFFF0000u), s, a[7]);
}
__device__ __forceinline__ sh8 hi8(const float4 a, const float4 b) {
  sh8 r;
  r[0] = (short)bfr(a.x); r[1] = (short)bfr(a.y);
  r[2] = (short)bfr(a.z); r[3] = (short)bfr(a.w);
  r[4] = (short)bfr(b.x); r[5] = (short)bfr(b.y);
  r[6] = (short)bfr(b.z); r[7] = (short)bfr(b.w);
  return r;
}

// ---------------- W pack helper ----------------
// Bp[((ks*CG + g)*64 + lane)*8 + j]; k=(ks&3)*32+(lane>>4)*8+j, n=g*16+(lane&15)
// hi for ks<4, lo residue for ks>=4.

template <int COUT>
__device__ __forceinline__ void packone(const float* __restrict__ W,
                                        ushortT* __restrict__ Bp, int i) {
  const int j = i & 7;
  const int l = (i >> 3) & 63;
  const int rest = i >> 9;
  const int g = rest % (COUT / 16);
  const int ks = rest / (COUT / 16);
  const int k = (ks & 3) * 32 + (l >> 4) * 8 + j;
  const int n = g * 16 + (l & 15);
  const float v = W[k * COUT + n];
  const unsigned short h = bfr(v);
  Bp[i] = (ks < 4) ? h : bfr(v - bf2f(h));
}

// ---------------- fused scatter (padded buckets) + weight pack ---------------
// Pairs packed to 4 B: (src << 8) | (dst & 255). R4-proven: converts random
// scatter into coalesced bucket runs (R5's direct atomics hit 64B-granule
// write amplification, 0.93 TB/s).

__global__ __launch_bounds__(256) void k_scatterpack(
    const int* __restrict__ src, const int* __restrict__ dst,
    int* __restrict__ cursor, unsigned* __restrict__ pairArr,
    const float* __restrict__ W1, const float* __restrict__ W2,
    const float* __restrict__ W3, ushortT* __restrict__ Bp1,
    ushortT* __restrict__ Bp2, ushortT* __restrict__ Bp3) {
  if (blockIdx.x >= SCB) {
    const int i = (blockIdx.x - SCB) * 256 + threadIdx.x;  // 0..81919
    if (i < 32768) packone<128>(W1, Bp1, i);
    else if (i < 65536) packone<128>(W2, Bp2, i - 32768);
    else packone<64>(W3, Bp3, i - 65536);
    return;
  }
  __shared__ int lcnt[512];   // NBK padded to 512 (zeros beyond) for paired scan
  __shared__ int lbase[512];
  __shared__ int lrank[NBK];
  __shared__ int bbase[NBK];
  __shared__ int sd2[256];
  __shared__ unsigned sorted[4096];
  __shared__ int target[4096];
  const int t = threadIdx.x;
  for (int i = t; i < 512; i += 256) lcnt[i] = 0;
  for (int i = t; i < NBK; i += 256) lrank[i] = 0;
  __syncthreads();
  const int base = blockIdx.x * 4096;
  int rs[16], rd[16];
#pragma unroll
  for (int q = 0; q < 16; q++) {
    int e = base + t + 256 * q;
    rs[q] = (e < NE) ? src[e] : -1;
    rd[q] = (e < NE) ? dst[e] : -1;
    if (rd[q] >= 0) atomicAdd(&lcnt[rd[q] >> BSH], 1);
  }
  __syncthreads();
  // 256-wide paired exclusive scan of lcnt[0..511]
  const int s0 = lcnt[2 * t];
  const int s1 = lcnt[2 * t + 1];
  sd2[t] = s0 + s1;
  __syncthreads();
  for (int off = 1; off < 256; off <<= 1) {
    int x = (t >= off) ? sd2[t - off] : 0;
    __syncthreads();
    sd2[t] += x;
    __syncthreads();
  }
  const int epair = sd2[t] - (s0 + s1);
  lbase[2 * t] = epair;
  lbase[2 * t + 1] = epair + s0;
  __syncthreads();
  for (int i = t; i < NBK; i += 256)
    if (lcnt[i] > 0) bbase[i] = atomicAdd(&cursor[i], lcnt[i]);
  __syncthreads();
#pragma unroll
  for (int q = 0; q < 16; q++) {
    if (rd[q] >= 0) {
      int b = rd[q] >> BSH;
      int r = atomicAdd(&lrank[b], 1);
      int slot = lbase[b] + r;
      sorted[slot] = ((unsigned)rs[q] << 8) | ((unsigned)rd[q] & 255u);
      target[slot] = b * CAP + bbase[b] + r;  // padded-bucket placement
    }
  }
  __syncthreads();
  const int n = min(4096, NE - base);
  for (int s = t; s < n; s += 256) pairArr[target[s]] = sorted[s];
}

// ---------------- MERGED: CSR build (blocks 0..390) || gemm1 (391+) ----------
// gemm1 (X@W1, UNSCALED — dinv applied per-edge in aggemm<128>) has no
// dependency on the CSR, so it fills the CUs while the 391 low-parallelism
// buildcsr blocks run their scans. R6-proven: saved ~25-30 us.

__global__ __launch_bounds__(256) void k_csrgemm1(
    const unsigned* __restrict__ pairArr, const int* __restrict__ cnt,
    float* __restrict__ dinv, int* __restrict__ rowptr, int* __restrict__ col,
    const float* __restrict__ X, const ushortT* __restrict__ Bp,
    ushortT* __restrict__ hs) {
  __shared__ int lc[256];
  __shared__ int sd[256];
  __shared__ int bc[NBK];
  const int t = threadIdx.x;
  if (blockIdx.x < NBK) {
    // ---- buildcsr arm (R4 verbatim) ----
    const int b = blockIdx.x;
    const int n0 = b << BSH;
    for (int i = t; i < NBK; i += 256) bc[i] = cnt[i];
    lc[t] = 0;
    __syncthreads();
    int partial = 0;
    for (int i = t; i < b; i += 256) partial += bc[i];
    sd[t] = partial;
    __syncthreads();
    for (int off = 128; off > 0; off >>= 1) {
      if (t < off) sd[t] += sd[t + off];
      __syncthreads();
    }
    const int ebeg = sd[0];
    const int myCnt = bc[b];
    __syncthreads();
    const unsigned* pb = pairArr + (size_t)b * CAP;
    for (int i = t; i < myCnt; i += 256)
      atomicAdd(&lc[pb[i] & 255u], 1);
    __syncthreads();
    const int v = lc[t];
    sd[t] = v;
    __syncthreads();
    for (int off = 1; off < 256; off <<= 1) {
      int x = (t >= off) ? sd[t - off] : 0;
      __syncthreads();
      sd[t] += x;
      __syncthreads();
    }
    const int excl = sd[t] - v;
    lc[t] = excl;
    const int node = n0 + t;
    if (node < NN) {
      rowptr[node] = ebeg + excl;
      dinv[node] = rsqrtf(1.0f + (float)v);  // self-loop => deg >= 1
    }
    if (b == 0 && t == 0) rowptr[NN] = NE;
    __syncthreads();
    for (int i = t; i < myCnt; i += 256) {
      unsigned p = pb[i];
      int d = (int)(p & 255u);
      int srcv = (int)(p >> 8);
      int pos = atomicAdd(&lc[d], 1);
      col[ebeg + pos] = srcv;
    }
    return;
  }
  // ---- gemm1 arm: hs1 = bf16( X @ W1 ), unscaled ----
  constexpr int CGALL = 8;  // 128/16
  constexpr int RG = 2;
  constexpr int CG = 4;
  const int bid = blockIdx.x - NBK;
  const int w = t >> 6;
  const int lane = t & 63;
  const int q = lane >> 4;
  const int c = lane & 15;
  const int row0 = bid * 64 + (w & 1) * 32;
  const int cg0 = (w >> 1) * 4;

  const float* xp[RG];
#pragma unroll
  for (int rg = 0; rg < RG; rg++) {
    const int row = row0 + rg * 16 + c;
    xp[rg] = X + (size_t)min(row, NN - 1) * 128 + q * 8;
  }
  const ushortT* bp0 = Bp + (size_t)lane * 8;

  f4 acc[RG][CG];
#pragma unroll
  for (int i = 0; i < RG; i++)
#pragma unroll
    for (int j = 0; j < CG; j++) acc[i][j] = (f4){0.f, 0.f, 0.f, 0.f};

  sh8 ah[RG], bh[CG], bl[CG];
  sh8 nah[RG], nbh[CG], nbl[CG];

  auto loadA = [&](int kr, sh8 (&h)[RG]) {
#pragma unroll
    for (int rg = 0; rg < RG; rg++) {
      const float4 x0 = *reinterpret_cast<const float4*>(xp[rg] + kr * 32);
      const float4 x1 = *reinterpret_cast<const float4*>(xp[rg] + kr * 32 + 4);
      h[rg] = hi8(x0, x1);
    }
  };
  auto loadB = [&](int kr, sh8 (&h)[CG], sh8 (&l)[CG]) {
#pragma unroll
    for (int cg = 0; cg < CG; cg++) {
      h[cg] = *reinterpret_cast<const sh8*>(bp0 + (size_t)(kr * CGALL + cg0 + cg) * 512);
      l[cg] = *reinterpret_cast<const sh8*>(bp0 + (size_t)((4 + kr) * CGALL + cg0 + cg) * 512);
    }
  };

  loadA(0, ah);
  loadB(0, bh, bl);
#pragma unroll
  for (int kr = 0; kr < 4; kr++) {
    if (kr < 3) {
      loadA(kr + 1, nah);
      loadB(kr + 1, nbh, nbl);
    }
#pragma unroll
    for (int rg = 0; rg < RG; rg++)
#pragma unroll
      for (int cg = 0; cg < CG; cg++)
        acc[rg][cg] = __builtin_amdgcn_mfma_f32_16x16x32_bf16(ah[rg], bh[cg],
                                                              acc[rg][cg], 0, 0, 0);
#pragma unroll
    for (int rg = 0; rg < RG; rg++)
#pragma unroll
      for (int cg = 0; cg < CG; cg++)
        acc[rg][cg] = __builtin_amdgcn_mfma_f32_16x16x32_bf16(ah[rg], bl[cg],
                                                              acc[rg][cg], 0, 0, 0);
    if (kr < 3) {
#pragma unroll
      for (int rg = 0; rg < RG; rg++) ah[rg] = nah[rg];
#pragma unroll
      for (int cg = 0; cg < CG; cg++) { bh[cg] = nbh[cg]; bl[cg] = nbl[cg]; }
    }
  }

#pragma unroll
  for (int rg = 0; rg < RG; rg++) {
#pragma unroll
    for (int reg = 0; reg < 4; reg++) {
      const int row = row0 + rg * 16 + q * 4 + reg;
      if (row < NN) {
#pragma unroll
        for (int cg = 0; cg < CG; cg++) {
          hs[(size_t)row * 128 + (cg0 + cg) * 16 + c] = bfr(acc[rg][cg][reg]);
        }
      }
    }
  }
}

// ---------------- FUSED aggregate + next-layer GEMM (v3, R4-proven) ----------
// Block = 16 nodes, 256 threads = 4 waves; wave w aggregates 4 nodes (short
// serial chain), rowptr/dinv prefetched via lane-parallel load + shfl.
// 256-thr granularity keeps 8 block slots/CU staggered pipeline. Results ->
// 4 KB swizzled LDS tile; one barrier; GEMM: 16 rows x COUT shared across the
// 4 waves (64 MFMAs/block — R6's per-wave replication quadrupled that and
// regressed 76->115 us; the waste lands serially inside each wave).
// ESCALE: hs_in unscaled; apply dinv[src] per edge (L2-resident, R6-proven).

template <int COUT, bool ESCALE>
__global__ __launch_bounds__(256, 8) void k_aggemm(
    const ushortT* __restrict__ hs_in, const int* __restrict__ rowptr,
    const int* __restrict__ col, const float* __restrict__ dinv,
    const float* __restrict__ bias, const ushortT* __restrict__ Bp,
    ushortT* __restrict__ hs_out) {
  constexpr int CGALL = COUT / 16;   // 8 or 4
  constexpr int UPW = CGALL / 4;     // MFMA units per wave: 2 or 1
  __shared__ ushortT At[16 * 128];   // 4 KB bf16 tile, swizzled
  const int t = threadIdx.x;
  const int w = t >> 6;        // wave 0..3
  const int lane = t & 63;
  const int q = lane >> 4;
  const int c = lane & 15;
  const int chb = c * 8;
  const int n0 = blockIdx.x * 16;
  const int nw0 = n0 + w * 4;  // first node of this wave

  // ---- prefetch per-wave metadata (rowptr[0..4], dinv[0..3] of nw0) ----
  const int rpv = rowptr[min(nw0 + (lane & 7), NN)];      // lanes 0..4 useful
  const float dvv = dinv[min(nw0 + (lane & 3), NN - 1)];
  const float4 b0 = *reinterpret_cast<const float4*>(bias + chb);
  const float4 b1 = *reinterpret_cast<const float4*>(bias + chb + 4);

  // ---- phase 1: aggregate 4 nodes per wave into LDS ----
  for (int it = 0; it < 4; ++it) {
    const int node = nw0 + it;   // always < NN (NB16*16 == NN)
    const int r = w * 4 + it;    // LDS row 0..15
    const int beg = __shfl(rpv, it);
    const int end = __shfl(rpv, it + 1);
    const float di = __shfl(dvv, it);
    float a[8] = {};
    if (q == 0) {  // self-loop
      const uint4 v = *reinterpret_cast<const uint4*>(hs_in + (long)node * 128 + chb);
      if (ESCALE) fma8(v, di, a); else acc8(v, a);
    }
    int j = beg;
    if (j + 8 <= end) {
      int c0 = col[j + q];
      int c1 = col[j + 4 + q];
      float d0 = 0.f, d1 = 0.f;
      if (ESCALE) { d0 = dinv[c0]; d1 = dinv[c1]; }
      while (true) {
        const uint4 v0 = *reinterpret_cast<const uint4*>(hs_in + (long)c0 * 128 + chb);
        const uint4 v1 = *reinterpret_cast<const uint4*>(hs_in + (long)c1 * 128 + chb);
        j += 8;
        const bool more = (j + 8 <= end);
        int m0, m1;
        float e0 = 0.f, e1 = 0.f;
        if (more) {
          m0 = col[j + q]; m1 = col[j + 4 + q];
          if (ESCALE) { e0 = dinv[m0]; e1 = dinv[m1]; }
        }
        if (ESCALE) { fma8(v0, d0, a); fma8(v1, d1, a); }
        else { acc8(v0, a); acc8(v1, a); }
        if (!more) break;
        c0 = m0; c1 = m1; d0 = e0; d1 = e1;
      }
    }
    if (j + 4 <= end) {
      int cc = col[j + q];
      const float ds = ESCALE ? dinv[cc] : 0.f;
      const uint4 v = *reinterpret_cast<const uint4*>(hs_in + (long)cc * 128 + chb);
      if (ESCALE) fma8(v, ds, a); else acc8(v, a);
      j += 4;
    }
    {
      const int rem = end - j;  // 0..3
      if (q < rem) {
        int cc = col[j + q];
        const float ds = ESCALE ? dinv[cc] : 0.f;
        const uint4 v = *reinterpret_cast<const uint4*>(hs_in + (long)cc * 128 + chb);
        if (ESCALE) fma8(v, ds, a); else acc8(v, a);
      }
    }
#pragma unroll
    for (int i = 0; i < 8; i++) a[i] += __shfl(a[i], lane ^ 32);
#pragma unroll
    for (int i = 0; i < 8; i++) a[i] += __shfl(a[i], lane ^ 16);
    if (q == 0) {
      float o[8];
      o[0] = fmaf(a[0], di, b0.x); o[1] = fmaf(a[1], di, b0.y);
      o[2] = fmaf(a[2], di, b0.z); o[3] = fmaf(a[3], di, b0.w);
      o[4] = fmaf(a[4], di, b1.x); o[5] = fmaf(a[5], di, b1.y);
      o[6] = fmaf(a[6], di, b1.z); o[7] = fmaf(a[7], di, b1.w);
#pragma unroll
      for (int i = 0; i < 8; i++) o[i] = fmaxf(o[i], 0.f);  // relu (layers 1,2)
      uint4 H;
      H.x = (unsigned)bfr(o[0]) | ((unsigned)bfr(o[1]) << 16);
      H.y = (unsigned)bfr(o[2]) | ((unsigned)bfr(o[3]) << 16);
      H.z = (unsigned)bfr(o[4]) | ((unsigned)bfr(o[5]) << 16);
      H.w = (unsigned)bfr(o[6]) | ((unsigned)bfr(o[7]) << 16);
      const unsigned bo = (unsigned)(r * 256 + c * 16) ^ (unsigned)((r & 7) << 4);
      *reinterpret_cast<uint4*>(reinterpret_cast<char*>(At) + bo) = H;
    }
  }
  __syncthreads();

  // ---- phase 2: GEMM, 16 rows x COUT; wave w owns col-groups w*UPW.. ----
  const int cg0 = w * UPW;
  const ushortT* bp0 = Bp + (size_t)lane * 8;
  const char* ab = reinterpret_cast<const char*>(At);
  const int arow = c;  // A-frag row: m = lane&15
  f4 acc[UPW];
#pragma unroll
  for (int u = 0; u < UPW; ++u) acc[u] = (f4){0.f, 0.f, 0.f, 0.f};
#pragma unroll
  for (int kr = 0; kr < 4; ++kr) {
    const unsigned bo =
        (unsigned)(arow * 256 + kr * 64 + q * 16) ^ (unsigned)((arow & 7) << 4);
    const sh8 af = *reinterpret_cast<const sh8*>(ab + bo);
#pragma unroll
    for (int u = 0; u < UPW; ++u) {
      const sh8 bh = *reinterpret_cast<const sh8*>(
          bp0 + (size_t)(kr * CGALL + cg0 + u) * 512);
      acc[u] = __builtin_amdgcn_mfma_f32_16x16x32_bf16(af, bh, acc[u], 0, 0, 0);
    }
#pragma unroll
    for (int u = 0; u < UPW; ++u) {
      const sh8 bl = *reinterpret_cast<const sh8*>(
          bp0 + (size_t)((4 + kr) * CGALL + cg0 + u) * 512);
      acc[u] = __builtin_amdgcn_mfma_f32_16x16x32_bf16(af, bl, acc[u], 0, 0, 0);
    }
  }
  // epilogue: scale by dinv[row] (pre-scale for next agg), round, store
#pragma unroll
  for (int reg = 0; reg < 4; ++reg) {
    const int row = n0 + q * 4 + reg;  // C/D row = quad*4+reg [m89]; < NN
    const float dv = dinv[row];
#pragma unroll
    for (int u = 0; u < UPW; ++u) {
      hs_out[(size_t)row * COUT + (cg0 + u) * 16 + c] = bfr(acc[u][reg] * dv);
    }
  }
}

// ---------------- final aggregation (64 ch, fp32 out) ------------------------

__global__ __launch_bounds__(256) void k_agg64(const ushortT* __restrict__ hs,
                                               const int* __restrict__ rowptr,
                                               const int* __restrict__ col,
                                               const float* __restrict__ dinv,
                                               const float* __restrict__ bias,
                                               float* __restrict__ out) {
  const int gid = blockIdx.x * 256 + threadIdx.x;
  const int node = gid >> 6;
  if (node >= NN) return;
  const int lane = threadIdx.x & 63;
  const int o8 = lane >> 3;        // eighth 0..7
  const int chb = (lane & 7) * 8;  // 8 channels per lane
  const int beg = rowptr[node];
  const int end = rowptr[node + 1];

  float a[8] = {};
  if (o8 == 0) {  // self
    const uint4 v = *reinterpret_cast<const uint4*>(hs + (long)node * 64 + chb);
    acc8(v, a);
  }

  int j = beg;
  if (j + 16 <= end) {
    int c0 = col[j + o8];
    int c1 = col[j + 8 + o8];
    while (true) {
      const uint4 v0 = *reinterpret_cast<const uint4*>(hs + (long)c0 * 64 + chb);
      const uint4 v1 = *reinterpret_cast<const uint4*>(hs + (long)c1 * 64 + chb);
      j += 16;
      const bool more = (j + 16 <= end);
      int n0, n1;
      if (more) { n0 = col[j + o8]; n1 = col[j + 8 + o8]; }
      acc8(v0, a);
      acc8(v1, a);
      if (!more) break;
      c0 = n0; c1 = n1;
    }
  }
  for (; j + 8 <= end; j += 8) {
    int c = col[j + o8];
    const uint4 v = *reinterpret_cast<const uint4*>(hs + (long)c * 64 + chb);
    acc8(v, a);
  }
  {
    const int r = end - j;  // 0..7
    if (o8 < r) {
      int c = col[j + o8];
      const uint4 v = *reinterpret_cast<const uint4*>(hs + (long)c * 64 + chb);
      acc8(v, a);
    }
  }

#pragma unroll
  for (int i = 0; i < 8; i++) a[i] += __shfl(a[i], lane ^ 32);
#pragma unroll
  for (int i = 0; i < 8; i++) a[i] += __shfl(a[i], lane ^ 16);
#pragma unroll
  for (int i = 0; i < 8; i++) a[i] += __shfl(a[i], lane ^ 8);

  if (o8 == 0) {
    const float di = dinv[node];
    const float4 b0 = *reinterpret_cast<const float4*>(bias + chb);
    const float4 b1 = *reinterpret_cast<const float4*>(bias + chb + 4);
    float4 r0, r1;
    r0.x = fmaf(a[0], di, b0.x); r0.y = fmaf(a[1], di, b0.y);
    r0.z = fmaf(a[2], di, b0.z); r0.w = fmaf(a[3], di, b0.w);
    r1.x = fmaf(a[4], di, b1.x); r1.y = fmaf(a[5], di, b1.y);
    r1.z = fmaf(a[6], di, b1.z); r1.w = fmaf(a[7], di, b1.w);
    *reinterpret_cast<float4*>(out + (long)node * 64 + chb) = r0;
    *reinterpret_cast<float4*>(out + (long)node * 64 + chb + 4) = r1;
  }
}

// ---------------- launch ----------------

extern "C" void kernel_launch(void* const* d_in, const int* in_sizes, int n_in,
                              void* d_out, int out_size, void* d_ws, size_t ws_size,
                              hipStream_t stream) {
  const float* x  = (const float*)d_in[0];
  const int* ei   = (const int*)d_in[1];
  const float* W1 = (const float*)d_in[2];
  const float* b1 = (const float*)d_in[3];
  const float* W2 = (const float*)d_in[4];
  const float* b2 = (const float*)d_in[5];
  const float* W3 = (const float*)d_in[6];
  const float* b3 = (const float*)d_in[7];
  float* out = (float*)d_out;
  const int* srcp = ei;        // edge_index[0]
  const int* dstp = ei + NE;   // edge_index[1]

  char* wsb = (char*)d_ws;
  size_t off = 0;
  auto alloc = [&](size_t bytes) -> void* {
    void* p = wsb + off;
    off += (bytes + 255) & ~(size_t)255;
    return p;
  };
  ushortT* hs1 = (ushortT*)alloc((size_t)MPAD * 128 * 2);  // bf16 layer-1 transform
  ushortT* hs2 = (ushortT*)alloc((size_t)NN * 128 * 2);    // bf16 layer-2 transform
  int*   col    = (int*)alloc((size_t)NE * 4);
  int*   rowptr = (int*)alloc((size_t)(NN + 1) * 4);
  float* dinv   = (float*)alloc((size_t)NN * 4);
  int*   cursor = (int*)alloc((size_t)NBK * 4);
  ushortT* Bp1 = (ushortT*)alloc((size_t)32768 * 2);  // 8 seg x 8 cg x 512
  ushortT* Bp2 = (ushortT*)alloc((size_t)32768 * 2);
  ushortT* Bp3 = (ushortT*)alloc((size_t)16384 * 2);  // 8 seg x 4 cg x 512
  // Aliases (sequential-kernel lifetimes):
  //   pairArr (391*5120*4 = 8 MB) lives in hs2: written by scatterpack, read
  //     by csrgemm1's buildcsr arm, clobbered by k_aggemm<128>'s hs2 write.
  //   hs3 (NN*64*2 = 12.8 MB) lives in hs1: hs1 dead after k_aggemm<128>
  //     reads it; k_aggemm<64> then writes hs3 there, k_agg64 reads it.
  unsigned* pairArr = (unsigned*)hs2;
  ushortT* hs3 = hs1;
  (void)ws_size; (void)in_sizes; (void)n_in; (void)out_size;

  hipMemsetAsync(cursor, 0, (size_t)NBK * 4, stream);
  k_scatterpack<<<SCB + 320, 256, 0, stream>>>(srcp, dstp, cursor, pairArr,
                                               W1, W2, W3, Bp1, Bp2, Bp3);
  // CSR build (391 blocks) overlapped with layer-1 transform (1564 blocks)
  k_csrgemm1<<<NBK + G1B, 256, 0, stream>>>(pairArr, cursor, dinv, rowptr, col,
                                            x, Bp1, hs1);

  const int aggGrid = (NN * 64) / 256;   // 25000

  // agg layer1 (edge-scaled: hs1 unscaled) + transform layer2
  k_aggemm<128, true><<<NB16, 256, 0, stream>>>(hs1, rowptr, col, dinv, b1, Bp2, hs2);
  // agg layer2 (hs2 pre-scaled) + transform layer3 (128 -> 64)
  k_aggemm<64, false><<<NB16, 256, 0, stream>>>(hs2, rowptr, col, dinv, b2, Bp3, hs3);
  // final aggregation (no relu, fp32 out)
  k_agg64<<<aggGrid, 256, 0, stream>>>(hs3, rowptr, col, dinv, b3, out);
}